// Round 1
// baseline (727.227 us; speedup 1.0000x reference)
//
#include <hip/hip_runtime.h>
#include <hip/hip_bf16.h>

#define B_   128
#define S_   1024
#define NT_  258
#define TG_  256
#define LN2f 0.69314718056f

typedef __attribute__((ext_vector_type(8))) short bf8_t;   // 8 bf16 (4 VGPR) MFMA A/B frag
typedef __attribute__((ext_vector_type(4))) float f4_t;    // MFMA C/D frag
typedef __attribute__((ext_vector_type(4))) short s4_t;

__device__ __forceinline__ unsigned short f2bf(float f) {
  unsigned u = __float_as_uint(f);
  u += 0x7fffu + ((u >> 16) & 1u);          // RTNE
  return (unsigned short)(u >> 16);
}
__device__ __forceinline__ float bf2f(unsigned short s) {
  return __uint_as_float(((unsigned)s) << 16);
}

// ---------------------------------------------------------------------------
// Scan kernel: 8 blocks x 512 threads (8 waves). Block owns 16 batches.
// State a[b][k] = exp(la[b][k] - c_b) kept in LDS as bf16, double-buffered,
// element-swizzled k ^ ((b&7)<<3).  Per step: C = a @ expT (MFMA),
// a' = exp(em) * C (masked), occasional power-of-2 rescale tracked in esv.
// ---------------------------------------------------------------------------
__global__ __launch_bounds__(512, 2) void crf_scan(
    const float* __restrict__ logits, const float* __restrict__ trans,
    const int* __restrict__ y, float* __restrict__ ws)
{
  __shared__ __align__(16) unsigned short aL[8192];  // 2 x (16 x 256) bf16
  __shared__ __align__(16) int   earr[16];
  __shared__ float esumL[16];
  __shared__ float refL[16];

  const int tid = threadIdx.x;
  const int w  = tid >> 6;
  const int l  = tid & 63;
  const int bq = blockIdx.x * 16;
  const int lg = l >> 4;          // lane group 0..3
  const int lc = l & 15;          // lane col within group
  const int koffe = lg * 8;

  // ---- B preload (expT columns 32w+ti*16+lc), step-invariant, in registers
  bf8_t Bf[2][8];
#pragma unroll
  for (int ti = 0; ti < 2; ++ti) {
    const int n = 32*w + ti*16 + lc;
#pragma unroll
    for (int kk = 0; kk < 8; ++kk) {
      bf8_t bv;
#pragma unroll
      for (int e = 0; e < 8; ++e) {
        const int k = kk*32 + koffe + e;
        bv[e] = (short)f2bf(__expf(trans[k*NT_ + n]));
      }
      Bf[ti][kk] = bv;
    }
  }

  // ---- address precompute (element indices into aL, swizzled)
  int idxA[8];
  {
    const int row = lc, sw = (row & 7) << 3;
#pragma unroll
    for (int kk = 0; kk < 8; ++kk)
      idxA[kk] = row*256 + ((kk*32 + koffe) ^ sw);
  }
  int idxW[2][4];
  int embase[2][4];
  int ybase[4];
#pragma unroll
  for (int r = 0; r < 4; ++r) {
    const int b = lg*4 + r;            // C-frag row: row = (lane>>4)*4 + reg
    ybase[r] = (bq + b) * S_;
#pragma unroll
    for (int ti = 0; ti < 2; ++ti) {
      const int j = 32*w + ti*16 + lc; // C-frag col: col = lane&15
      idxW[ti][r]   = b*256 + (j ^ ((b & 7) << 3));
      embase[ti][r] = (bq + b) * (S_*256) + j;
    }
  }

  // ---- init t=0: la0 = logits[:,0,:] + T[START,:]; a0 = exp(la0 - la0[0])
#pragma unroll
  for (int bb = 0; bb < 2; ++bb) {
    const int b = 2*w + bb;
    const float4 em0 = *(const float4*)&logits[(size_t)(bq + b) * (S_*256) + 4*l];
    const float4 ts4 = *(const float4*)&trans[TG_*NT_ + 4*l];
    const float la0 = em0.x + ts4.x, la1 = em0.y + ts4.y;
    const float la2 = em0.z + ts4.z, la3 = em0.w + ts4.w;
    const float ref = __shfl(la0, 0);
    if (l == 0) { refL[b] = ref; esumL[b] = 0.f; }
    s4_t s;
    s[0] = (short)f2bf(__expf(la0 - ref));
    s[1] = (short)f2bf(__expf(la1 - ref));
    s[2] = (short)f2bf(__expf(la2 - ref));
    s[3] = (short)f2bf(__expf(la3 - ref));
    *(s4_t*)&aL[b*256 + ((4*l) ^ ((b & 7) << 3))] = s;
  }

  // ---- prefetch em/y for t=1 (A set) and t=2 (B set)
  float emA[2][4], emB[2][4];
  int yA[4], yB[4];
#pragma unroll
  for (int r = 0; r < 4; ++r) {
    yA[r] = y[ybase[r] + 1];
    yB[r] = y[ybase[r] + 2];
#pragma unroll
    for (int ti = 0; ti < 2; ++ti) {
      emA[ti][r] = logits[embase[ti][r] + 1*256];
      emB[ti][r] = logits[embase[ti][r] + 2*256];
    }
  }
  float esv[4] = {0.f, 0.f, 0.f, 0.f};   // per-batch exponent sums (wave0 lc==0 lanes)

  __syncthreads();

// one step of the scan. CURE_/NXTE_ are element offsets (0 or 4096) of the
// a double-buffers. EMV_/YV_ are consumed for step T_ and refilled for T_+2.
#define SCAN_STEP(T_, CURE_, NXTE_, EMV_, YV_) do {                           \
  float F0_[4], F1_[4]; int m_[4];                                            \
  _Pragma("unroll") for (int r = 0; r < 4; ++r) {                             \
    F0_[r] = __expf(EMV_[0][r]); F1_[r] = __expf(EMV_[1][r]); m_[r] = YV_[r]; } \
  const int tp_ = ((T_)+2 < S_) ? ((T_)+2) : (S_-1);                          \
  _Pragma("unroll") for (int r = 0; r < 4; ++r) {                             \
    YV_[r] = y[ybase[r] + tp_];                                               \
    EMV_[0][r] = logits[embase[0][r] + tp_*256];                              \
    EMV_[1][r] = logits[embase[1][r] + tp_*256]; }                            \
  bf8_t Af_[8];                                                               \
  _Pragma("unroll") for (int kk = 0; kk < 8; ++kk)                            \
    Af_[kk] = *(const bf8_t*)&aL[(CURE_) + idxA[kk]];                         \
  f4_t c0_ = {0.f,0.f,0.f,0.f}, c1_ = {0.f,0.f,0.f,0.f};                      \
  _Pragma("unroll") for (int kk = 0; kk < 8; ++kk) {                          \
    c0_ = __builtin_amdgcn_mfma_f32_16x16x32_bf16(Af_[kk], Bf[0][kk], c0_, 0, 0, 0); \
    c1_ = __builtin_amdgcn_mfma_f32_16x16x32_bf16(Af_[kk], Bf[1][kk], c1_, 0, 0, 0); } \
  float v0_[4], v1_[4];                                                       \
  _Pragma("unroll") for (int r = 0; r < 4; ++r) {                             \
    v0_[r] = F0_[r]*c0_[r]; v1_[r] = F1_[r]*c1_[r]; }                         \
  if (((T_) & 7) == 0) {                   /* apply rescale published at T-1 */ \
    const int4 er_ = *(const int4*)&earr[lg*4];                               \
    v0_[0] = ldexpf(v0_[0], -er_.x); v1_[0] = ldexpf(v1_[0], -er_.x);         \
    v0_[1] = ldexpf(v0_[1], -er_.y); v1_[1] = ldexpf(v1_[1], -er_.y);         \
    v0_[2] = ldexpf(v0_[2], -er_.z); v1_[2] = ldexpf(v1_[2], -er_.z);         \
    v0_[3] = ldexpf(v0_[3], -er_.w); v1_[3] = ldexpf(v1_[3], -er_.w);         \
    if (w == 0 && lc == 0) {                                                  \
      if (m_[0] >= 0) esv[0] += (float)er_.x;                                 \
      if (m_[1] >= 0) esv[1] += (float)er_.y;                                 \
      if (m_[2] >= 0) esv[2] += (float)er_.z;                                 \
      if (m_[3] >= 0) esv[3] += (float)er_.w; } }                             \
  _Pragma("unroll") for (int r = 0; r < 4; ++r) {                             \
    if (m_[r] >= 0) {                       /* masked rows stay frozen */     \
      aL[(NXTE_) + idxW[0][r]] = f2bf(v0_[r]);                                \
      aL[(NXTE_) + idxW[1][r]] = f2bf(v1_[r]); } }                            \
  if (((T_) & 7) == 7 && w == 0 && lc == 0) {  /* publish exponent of a[b][0] */ \
    _Pragma("unroll") for (int r = 0; r < 4; ++r)                             \
      earr[lg*4 + r] = (int)((__float_as_uint(v0_[r]) >> 23) & 255) - 127; }  \
  asm volatile("s_waitcnt lgkmcnt(0)" ::: "memory");  /* LDS drain only —   */ \
  __builtin_amdgcn_s_barrier();                       /* keep global        */ \
  asm volatile("" ::: "memory");                      /* prefetch in flight */ \
} while (0)

  SCAN_STEP(1, 0, 4096, emA, yA);
#pragma unroll 1
  for (int tt = 2; tt < S_; tt += 2) {
    SCAN_STEP(tt,   4096, 0, emB, yB);
    SCAN_STEP(tt+1, 0, 4096, emA, yA);
  }
#undef SCAN_STEP

  // ---- finalize: log_z[b] = log( sum_j a[b][j]*exp(T[j,END]) ) + esum*ln2 + ref
  if (w == 0 && lc == 0) {
#pragma unroll
    for (int r = 0; r < 4; ++r) esumL[lg*4 + r] = esv[r];
  }
  __syncthreads();
#pragma unroll
  for (int bb = 0; bb < 2; ++bb) {
    const int b = 2*w + bb;
    const s4_t s = *(const s4_t*)&aL[4096 + b*256 + ((4*l) ^ ((b & 7) << 3))];
    float p = 0.f;
#pragma unroll
    for (int e = 0; e < 4; ++e) {
      const int k = 4*l + e;
      p += bf2f((unsigned short)s[e]) * __expf(trans[k*NT_ + 257]);
    }
#pragma unroll
    for (int o = 32; o; o >>= 1) p += __shfl_xor(p, o);
    if (l == 0)
      ws[128 + bq + b] = __logf(p) + esumL[b]*LN2f + refL[b];
  }
}

// ---------------------------------------------------------------------------
// llh (gold-path score) + lengths: 128 blocks x 256 threads, t-parallel.
// ---------------------------------------------------------------------------
__global__ void crf_llh(const float* __restrict__ logits, const float* __restrict__ trans,
                        const int* __restrict__ y, float* __restrict__ ws)
{
  const int b = blockIdx.x, tid = threadIdx.x;
  const int yb = b * S_;
  float part = 0.f; int cnt = 0;
  for (int t = tid; t < S_; t += 256) {
    const int yt = y[yb + t];
    const bool m = (yt >= 0);
    if (m) ++cnt;
    if (t == 0) {
      const int tag0 = m ? yt : 0;
      part += trans[TG_*NT_ + tag0];                       // T[START, y0]
      if (m) part += logits[(size_t)yb * 256 + tag0];
    } else if (m) {
      const int yp = y[yb + t - 1];                        // mask monotone => valid
      part += logits[((size_t)(yb + t)) * 256 + yt] + trans[yp*NT_ + yt];
    }
    if (m && (t + 1 == S_ || y[yb + t + 1] < 0))
      part += trans[yt*NT_ + 257];                         // T[last, END]
  }
#pragma unroll
  for (int o = 32; o; o >>= 1) { part += __shfl_xor(part, o); cnt += __shfl_xor(cnt, o); }
  __shared__ float sp[4]; __shared__ int sc[4];
  if ((tid & 63) == 0) { sp[tid >> 6] = part; sc[tid >> 6] = cnt; }
  __syncthreads();
  if (tid == 0) {
    ws[b]       = sp[0] + sp[1] + sp[2] + sp[3];
    ws[256 + b] = (float)(sc[0] + sc[1] + sc[2] + sc[3]);
  }
}

// ---------------------------------------------------------------------------
// loss = mean_b( -(llh - log_z)/len )
// ---------------------------------------------------------------------------
__global__ void crf_fin(const float* __restrict__ ws, float* __restrict__ out)
{
  const int i = threadIdx.x;  // 128
  float v = -(ws[i] - ws[128 + i]) / ws[256 + i];
#pragma unroll
  for (int o = 32; o; o >>= 1) v += __shfl_xor(v, o);
  __shared__ float s2[2];
  if ((i & 63) == 0) s2[i >> 6] = v;
  __syncthreads();
  if (i == 0) out[0] = (s2[0] + s2[1]) * (1.0f / 128.0f);
}

extern "C" void kernel_launch(void* const* d_in, const int* in_sizes, int n_in,
                              void* d_out, int out_size, void* d_ws, size_t ws_size,
                              hipStream_t stream)
{
  const float* logits = (const float*)d_in[0];
  const float* trans  = (const float*)d_in[1];
  const int*   y      = (const int*)d_in[2];
  float* ws  = (float*)d_ws;   // [0,128) llh | [128,256) log_z | [256,384) len
  float* out = (float*)d_out;

  hipLaunchKernelGGL(crf_llh,  dim3(128), dim3(256), 0, stream, logits, trans, y, ws);
  hipLaunchKernelGGL(crf_scan, dim3(8),   dim3(512), 0, stream, logits, trans, y, ws);
  hipLaunchKernelGGL(crf_fin,  dim3(1),   dim3(128), 0, stream, ws, out);
}